// Round 9
// baseline (564.408 us; speedup 1.0000x reference)
//
#include <hip/hip_runtime.h>
#include <hip/hip_cooperative_groups.h>
#include <math.h>

namespace cg = cooperative_groups;

// Problem constants
#define DIMS   6
#define NGEO   20
#define NPHI   27
#define NEXPERT 540
#define MPTS   256
#define NTEST  1024
#define NMAT   560          // experts + baselines
#define JIT    1e-4f
#define USTRIDE 33280       // packed padded upper-triangular floats per matrix
#define L2E    1.44269504088896340736f

// Row j of U (cols j..255) starts at uoff(j); each row padded to 4-float multiple.
__device__ __forceinline__ int uoff(int j){
    int m = j >> 2, r = j & 3;
    return 1024*m - 8*m*(m-1) + r*(256 - 4*m);
}

// ---------------------------------------------------------------------------
// MEGA KERNEL (cooperative): phase1 prep+route (blocks 0,1) -> grid.sync ->
// phase2 compact (block 0) -> grid.sync -> phase3 chol (frozen r2 237us
// code) -> grid.sync -> phase4 predict. Removes 4 of 5 launch overheads
// (residual was a CONSTANT 165us across r2/r5/r7/r8 -> launch/sync +
// predict, not chol-dependent). 256 blocks x 512 thr, ~112KB LDS ->
// 1 block/CU, exactly the cooperative co-residency requirement.
// ---------------------------------------------------------------------------
__global__ __launch_bounds__(512)
void mega_kernel(const float* __restrict__ Xt,
                 const float* __restrict__ X_exp, const float* __restrict__ Y_exp,
                 const float* __restrict__ X_base, const float* __restrict__ Y_base,
                 const float* __restrict__ lls_e, const float* __restrict__ los_e,
                 const float* __restrict__ lno_e,
                 const float* __restrict__ lls_b, const float* __restrict__ los_b,
                 const float* __restrict__ lno_b,
                 const float* __restrict__ sm, const float* __restrict__ ss,
                 const float* __restrict__ gm, const float* __restrict__ glv,
                 const float* __restrict__ glw,
                 const float* __restrict__ pm, const float* __restrict__ plv,
                 const float* __restrict__ plw,
                 const int* __restrict__ nmask,
                 float* __restrict__ Uws, float* __restrict__ Vws,
                 int* __restrict__ e_idx, int* __restrict__ g_idx,
                 int* __restrict__ list, int* __restrict__ cnt,
                 float* __restrict__ out)
{
    cg::grid_group grid = cg::this_grid();
    int t = threadIdx.x;
    int b = blockIdx.x;

    // ---- LDS (sum ~112 KB; all phases' arrays coexist) ----
    __shared__ __align__(16) float Xs[256*8];    //  8 KB  chol: train points
    __shared__ __align__(16) float Bs[7*1024];   // 28 KB  chol: staged B blocks
    __shared__ __align__(16) float Part[256*36]; // 36 KB  chol: secondary partials
    __shared__ float Dl[32*36];                  // chol: diag block of L
    __shared__ float Dinv[32];                   // chol: 1/diag(L)
    __shared__ double EpL[NGEO*NPHI*DIMS];       // 25.9 KB route tables
    __shared__ double EgL[NGEO*DIMS];
    __shared__ double S1gL[NGEO];
    __shared__ double S1pL[NGEO*NPHI];
    __shared__ int flags[NMAT];                  // compact
    __shared__ int ssum[512];                    // compact scan
    __shared__ float res8[8][4];                 // predict per-wave results

    // ================= phase 1: prep tables + route (blocks 0,1) ==========
    if (b < 2){
        if (t < NGEO*DIMS) EgL[t] = exp(-(double)glv[t]);
        for (int i=t; i<NGEO*NPHI*DIMS; i+=512) EpL[i] = exp(-(double)plv[i]);
        if (t < NGEO){
            double s = 0.0;
            #pragma unroll
            for (int d=0; d<DIMS; d++) s += (double)glv[t*DIMS+d];
            S1gL[t] = s;
        }
        for (int i=t; i<NGEO*NPHI; i+=512){
            double s = 0.0;
            #pragma unroll
            for (int d=0; d<DIMS; d++) s += (double)plv[i*DIMS+d];
            S1pL[i] = s;
        }
        __syncthreads();
        int n = b*512 + t;                       // exactly covers 0..1023
        double xs[DIMS];
        #pragma unroll
        for (int d=0; d<DIMS; d++)
            xs[d] = ((double)Xt[n*DIMS+d] - (double)sm[d]) / (double)ss[d];
        const double cst = (double)DIMS * 1.8378770664093453;  // D*log(2*pi)

        int bg = 0; double best = -1e300;
        for (int j=0; j<NGEO; j++){
            double qd = 0.0;
            #pragma unroll
            for (int d=0; d<DIMS; d++){
                double df = xs[d] - (double)gm[j*DIMS+d];
                qd += df*df*EgL[j*DIMS+d];
            }
            double lp = (double)glw[j] - 0.5*(S1gL[j] + qd + cst);
            if (lp > best){ best = lp; bg = j; }
        }
        int bk = 0; best = -1e300;
        for (int k=0; k<NPHI; k++){
            double qd = 0.0;
            int o = (bg*NPHI + k)*DIMS;
            #pragma unroll
            for (int d=0; d<DIMS; d++){
                double df = xs[d] - (double)pm[o+d];
                qd += df*df*EpL[o+d];
            }
            double lp = (double)plw[bg*NPHI+k] - 0.5*(S1pL[bg*NPHI+k] + qd + cst);
            if (lp > best){ best = lp; bk = k; }
        }
        e_idx[n] = bg*NPHI + bk;
        g_idx[n] = bg;
    }
    grid.sync();

    // ================= phase 2: compact worklist (block 0) ================
    if (b == 0){
        for (int i=t; i<NMAT; i+=512) flags[i] = (i < NEXPERT) ? 0 : 1;
        __syncthreads();
        for (int i=t; i<NTEST; i+=512){
            int e = e_idx[i];
            if (nmask[e] != 0) flags[e] = 1;     // benign race: same value
        }
        __syncthreads();
        // pairwise scan: thread t owns elements 2t, 2t+1 (order-preserving)
        int f0 = (2*t     < NMAT) ? flags[2*t]     : 0;
        int f1 = (2*t + 1 < NMAT) ? flags[2*t + 1] : 0;
        ssum[t] = f0 + f1;
        __syncthreads();
        for (int off=1; off<512; off<<=1){
            int v = (t >= off) ? ssum[t-off] : 0;
            __syncthreads();
            ssum[t] += v;
            __syncthreads();
        }
        int excl = ssum[t] - (f0 + f1);
        if (f0) list[excl]      = 2*t;
        if (f1) list[excl + f0] = 2*t + 1;
        if (t == 511) cnt[0] = ssum[511];
    }
    grid.sync();

    // ================= phase 3: chol (FROZEN r2 237us code) ===============
    {
    int w = t >> 6, lane = t & 63;
    bool prim = (t < 256);
    int nwork = cnt[0];

    for (int item = b; item < nwork; item += gridDim.x){
    int mat = list[item];
    int q = ((w & 3) + item) & 3;                // column chunk (team-matched)
    int c = 64*q + lane;                         // owned column

    const float *Xtr, *Ytr;
    float lls, los, lno;
    if (mat < NEXPERT){
        Xtr = X_exp + mat*(MPTS*DIMS); Ytr = Y_exp + mat*MPTS;
        lls = lls_e[mat]; los = los_e[mat]; lno = lno_e[mat];
    } else {
        int g = mat - NEXPERT;
        Xtr = X_base + g*(MPTS*DIMS); Ytr = Y_base + g*MPTS;
        lls = lls_b[g]; los = los_b[g]; lno = lno_b[g];
    }
    float ls2 = expf(2.f*lls);
    float os  = expf(los);
    float nv  = expf(lno) + JIT;
    float c1  = -0.5f*L2E/ls2;
    float* Ug = Uws + (size_t)mat*USTRIDE;

    // stage X into LDS (padded stride 8; slots 6,7 never read)
    for (int i=t; i<MPTS*DIMS; i+=512){ int r=i/DIMS, d=i-r*DIMS; Xs[r*8+d]=Xtr[i]; }

    for (int j=0; j<8; j++){
        __syncthreads();   // prev panel's Bs/Part reads done + stores drained

        // ---- async-stage B blocks for this panel (all 8 waves) ----
        for (int u=w; u<16*j; u+=8){
            int blk = u >> 4, e0 = (u & 15)*64;
            int m  = 2*(u & 15) + (lane >> 5);
            int kk = lane & 31;
            int ri = 32*blk + m;
            const float* gp = Ug + (uoff(ri) + 32*j + kk - ri);
            __builtin_amdgcn_global_load_lds(
                (const __attribute__((address_space(1))) void*)gp,
                (__attribute__((address_space(3))) void*)&Bs[blk*1024 + e0],
                4, 0, 0);
        }

        int l = c - 32*j;                // diag-local index of owned column
        bool act = (l >= 0);
        int jh = j >> 1;                 // primary panels: [0,jh); secondary: [jh,j)
        float x[32];                     // primary: column value; secondary: partial

        // ---- build original K entries (primary; overlaps staging) ----
        if (prim && act){
            float4 xa = *(const float4*)&Xs[c*8];
            float2 xb = *(const float2*)&Xs[c*8+4];
            #pragma unroll
            for (int k=0; k<32; k++){
                const float* Xr = &Xs[(32*j+k)*8];
                float4 ra = *(const float4*)Xr;
                float2 rb = *(const float2*)(Xr+4);
                float d0=xa.x-ra.x, d1=xa.y-ra.y, d2v=xa.z-ra.z, d3=xa.w-ra.w;
                float d4=xb.x-rb.x, d5=xb.y-rb.y;
                float dd = d0*d0+d1*d1+d2v*d2v+d3*d3+d4*d4+d5*d5;
                float val = os*exp2f(c1*dd);
                if (k == l) val += nv;   // diagonal
                x[k] = val;
            }
        } else {
            #pragma unroll
            for (int k=0; k<32; k++) x[k] = 0.f;   // secondary partial
        }
        __syncthreads();   // staging drained (vmcnt 0) -> Bs valid

        // ---- update: team-split over prev panels ----
        if (act){
            int i0 = prim ? 0 : jh;
            int i1 = prim ? jh : j;
            for (int i2=i0; i2<i1; i2++){
                float a[32];
                #pragma unroll
                for (int m=0; m<32; m++){
                    int ri = 32*i2 + m;
                    a[m] = Ug[uoff(ri) + c - ri];     // U[ri][c]
                }
                #pragma unroll 8
                for (int m=0; m<32; m++){
                    const float4* Bp = (const float4*)&Bs[i2*1024 + m*32];
                    float nam = -a[m];
                    #pragma unroll
                    for (int kk=0; kk<8; kk++){
                        float4 bb = Bp[kk];           // broadcast, conflict-free
                        x[kk*4+0] = fmaf(bb.x, nam, x[kk*4+0]);
                        x[kk*4+1] = fmaf(bb.y, nam, x[kk*4+1]);
                        x[kk*4+2] = fmaf(bb.z, nam, x[kk*4+2]);
                        x[kk*4+3] = fmaf(bb.w, nam, x[kk*4+3]);
                    }
                }
            }
            // secondary publishes its partial
            if (!prim && j > jh){
                float4* Pp = (float4*)&Part[c*36];
                #pragma unroll
                for (int kk=0; kk<8; kk++)
                    Pp[kk] = make_float4(x[kk*4+0], x[kk*4+1], x[kk*4+2], x[kk*4+3]);
            }
        }
        __syncthreads();   // Part ready

        // ---- combine (primary only) ----
        if (prim && act && j > jh){
            const float4* Pp = (const float4*)&Part[c*36];
            #pragma unroll
            for (int kk=0; kk<8; kk++){
                float4 pv = Pp[kk];
                x[kk*4+0] += pv.x; x[kk*4+1] += pv.y;
                x[kk*4+2] += pv.z; x[kk*4+3] += pv.w;
            }
        }

        // ---- diag 32x32 factor: owning primary half-wave, shfl only ----
        if (prim && l >= 0 && l < 32){
            int lb = 32*(j & 1);          // lane base of the diag group
            float r[32];
            #pragma unroll
            for (int k=0; k<32; k++) r[k] = (k <= l) ? x[k] : 0.f;
            float myinv = 1.f;
            #pragma unroll
            for (int cc=0; cc<32; cc++){
                float pivsq = __shfl(r[cc], lb + cc);
                float inv = rsqrtf(pivsq);
                r[cc] *= inv;
                if (l == cc) myinv = inv;
                #pragma unroll
                for (int k=cc+1; k<32; k++) r[k] -= r[cc]*__shfl(r[cc], lb + k);
            }
            Dinv[l] = myinv;
            #pragma unroll
            for (int k=0; k<32; k++){
                if (k <= l) Dl[l*36 + k] = r[k];
                x[k] = r[k];
            }
        }
        __syncthreads();                  // Dl/Dinv visible
        // ---- trsm: in-thread, D via LDS broadcast ----
        if (prim && l >= 32){
            #pragma unroll
            for (int cc=0; cc<32; cc++){
                float a = x[cc]*Dinv[cc];
                x[cc] = a;
                #pragma unroll
                for (int k=cc+1; k<32; k++)
                    x[k] -= Dl[k*36 + cc]*a;
            }
        }
        // ---- store panel column to global (once) ----
        if (prim && act){
            #pragma unroll
            for (int k=0; k<32; k++){
                if (l >= k) Ug[uoff(32*j+k) + l - k] = x[k];
            }
        }
    }
    __syncthreads();

    // v = L^-1 y  (forward solve, wave 0 only; L columns = U rows, coalesced)
    if (t < 64){
        int l = t;
        float z[4], rd[4];
        #pragma unroll
        for (int qq2=0; qq2<4; qq2++){
            z[qq2]  = Ytr[64*qq2 + l];
            rd[qq2] = 1.f/Ug[uoff(64*qq2 + l)];
        }
        int offj = 0;
        #pragma unroll
        for (int qq2=0; qq2<4; qq2++){
            for (int j2=0; j2<64; j2++){
                int j = 64*qq2 + j2;
                float zf = __shfl(z[qq2], j2) * __shfl(rd[qq2], j2);
                if (l == j2) z[qq2] = zf;
                #pragma unroll
                for (int r=qq2; r<4; r++){
                    int dd = 64*(r-qq2) + (l - j2);
                    int dc = dd > 0 ? dd : 0;
                    float uv = Ug[offj + dc];
                    if (dd > 0) z[r] -= uv*zf;
                }
                offj += (259-j)&~3;
            }
        }
        #pragma unroll
        for (int qq2=0; qq2<4; qq2++) Vws[mat*256 + 64*qq2 + l] = z[qq2];
    }
    __syncthreads();   // safe LDS reuse for next work item
    }
    }
    grid.sync();

    // ================= phase 4: predict + rBCM combine ====================
    {
    int lw = t >> 6, l = t & 63;
    for (int pb = b; pb*8 < 2*NTEST; pb += gridDim.x){
        int wt = pb*8 + lw, n = wt >> 1, side = wt & 1;

        int bidx; const float* Xtr; float lls, los, lno;
        bool isnull = false;
        if (side == 0){
            int ee = e_idx[n]; bidx = ee; Xtr = X_exp + ee*(MPTS*DIMS);
            lls = lls_e[ee]; los = los_e[ee]; lno = lno_e[ee];
            isnull = (nmask[ee] == 0);
        } else {
            int g = g_idx[n]; bidx = NEXPERT + g; Xtr = X_base + g*(MPTS*DIMS);
            lls = lls_b[g]; los = los_b[g]; lno = lno_b[g];
        }
        float ls2 = expf(2.f*lls), os = expf(los), nv = expf(lno) + JIT;
        float c1 = -0.5f*L2E/ls2;

        if (!isnull){   // wave-uniform branch
            float xt[DIMS];
            #pragma unroll
            for (int d=0; d<DIMS; d++) xt[d] = Xt[n*DIMS + d];

            const float* Ug = Uws + (size_t)bidx*USTRIDE;
            const float* vv = Vws + bidx*256;

            float z[4], rd[4];
            #pragma unroll
            for (int q=0; q<4; q++){
                int m = 64*q + l;
                float d2 = 0.f;
                #pragma unroll
                for (int d=0; d<DIMS; d++){ float df = xt[d]-Xtr[m*DIMS+d]; d2 += df*df; }
                z[q]  = os*exp2f(c1*d2);
                rd[q] = 1.f/Ug[uoff(m)];
            }
            // w = L^-1 k*  (forward solve, 4-column pivot groups)
            int offj = 0;
            #pragma unroll
            for (int q=0; q<4; q++){
                #pragma unroll 4
                for (int g=0; g<16; g++){
                    int j2 = 4*g;
                    int jr = 64*q + j2;
                    int off0 = offj;
                    int off1 = off0 + ((259-jr)&~3);
                    int off2 = off1 + ((258-jr)&~3);
                    int off3 = off2 + ((257-jr)&~3);
                    float a0 = __shfl(z[q], j2+0), a1 = __shfl(z[q], j2+1);
                    float a2 = __shfl(z[q], j2+2), a3 = __shfl(z[q], j2+3);
                    float r0 = __shfl(rd[q], j2+0), r1 = __shfl(rd[q], j2+1);
                    float r2 = __shfl(rd[q], j2+2), r3 = __shfl(rd[q], j2+3);
                    float L10 = Ug[off0+1], L20 = Ug[off0+2], L30 = Ug[off0+3];
                    float L21 = Ug[off1+1], L31 = Ug[off1+2];
                    float L32 = Ug[off2+1];
                    float zf0 = a0*r0;
                    float zf1 = (a1 - L10*zf0)*r1;
                    float zf2 = ((a2 - L20*zf0) - L21*zf1)*r2;
                    float zf3 = (((a3 - L30*zf0) - L31*zf1) - L32*zf2)*r3;
                    if (l == j2+0) z[q] = zf0;
                    if (l == j2+1) z[q] = zf1;
                    if (l == j2+2) z[q] = zf2;
                    if (l == j2+3) z[q] = zf3;
                    if (l >= j2+4){
                        z[q] -= Ug[off0 + (l - j2)]*zf0;
                        z[q] -= Ug[off1 + (l - j2 - 1)]*zf1;
                        z[q] -= Ug[off2 + (l - j2 - 2)]*zf2;
                        z[q] -= Ug[off3 + (l - j2 - 3)]*zf3;
                    }
                    #pragma unroll
                    for (int r=q+1; r<4; r++){
                        int dd = 64*(r-q) + (l - j2);
                        z[r] -= Ug[off0 + dd]*zf0;
                        z[r] -= Ug[off1 + dd - 1]*zf1;
                        z[r] -= Ug[off2 + dd - 2]*zf2;
                        z[r] -= Ug[off3 + dd - 3]*zf3;
                    }
                    offj = off3 + ((256-jr)&~3);
                }
            }
            float qq = 0.f, mu = 0.f;
            #pragma unroll
            for (int q=0; q<4; q++){ qq += z[q]*z[q]; mu += z[q]*vv[64*q + l]; }
            #pragma unroll
            for (int o=32; o>0; o>>=1){ qq += __shfl_xor(qq, o); mu += __shfl_xor(mu, o); }
            if (l == 0){
                res8[lw][0] = mu;
                res8[lw][1] = fmaxf(os - qq, JIT) + nv;   // predictive var incl noise
                res8[lw][2] = os + nv;                    // prior
            }
        } else {
            if (l == 0){
                res8[lw][0] = 0.f;
                res8[lw][1] = os + nv;    // var = prior -> beta_e = 0, no NaN
                res8[lw][2] = os + nv;
            }
        }
        __syncthreads();
        if (t < 4){
            int pp = t, n2 = pb*4 + pp;
            float mu_e = res8[2*pp][0],   var_e = res8[2*pp][1],   pr_e = res8[2*pp][2];
            float mu_b = res8[2*pp+1][0], var_b = res8[2*pp+1][1], pr_b = res8[2*pp+1][2];
            int ee = e_idx[n2];
            float be = (nmask[ee] == 0) ? 0.f
                     : fmaxf(0.5f*(logf(pr_e) - logf(var_e)), 0.f);
            float bb = fmaxf(0.5f*(logf(pr_b) - logf(var_b)), 0.f);
            float prec = be/var_e + bb/var_b + (1.f - be - bb)/pr_b;
            prec = fmaxf(prec, 1e-6f);
            out[n2]         = (be*mu_e/var_e + bb*mu_b/var_b)/prec;
            out[NTEST + n2] = 1.f/prec;
        }
        __syncthreads();   // res8 safe for next grid-stride pass
    }
    }
}

// ---------------------------------------------------------------------------
extern "C" void kernel_launch(void* const* d_in, const int* in_sizes, int n_in,
                              void* d_out, int out_size, void* d_ws, size_t ws_size,
                              hipStream_t stream)
{
    const float* X_test  = (const float*)d_in[0];
    const float* X_exp   = (const float*)d_in[1];
    const float* Y_exp   = (const float*)d_in[2];
    const float* X_base  = (const float*)d_in[3];
    const float* Y_base  = (const float*)d_in[4];
    const float* lls_e   = (const float*)d_in[5];
    const float* los_e   = (const float*)d_in[6];
    const float* lno_e   = (const float*)d_in[7];
    const float* lls_b   = (const float*)d_in[8];
    const float* los_b   = (const float*)d_in[9];
    const float* lno_b   = (const float*)d_in[10];
    const float* sm      = (const float*)d_in[11];
    const float* ss      = (const float*)d_in[12];
    const float* gm      = (const float*)d_in[13];
    const float* glv     = (const float*)d_in[14];
    const float* glw     = (const float*)d_in[15];
    const float* pm      = (const float*)d_in[16];
    const float* plv     = (const float*)d_in[17];
    const float* plw     = (const float*)d_in[18];
    const int*   nmask   = (const int*)d_in[19];

    // ws layout kept identical to prior rounds (Eg..S1p slots now unused)
    double* Eg  = (double*)d_ws;                     // 120
    double* Ep  = Eg + NGEO*DIMS;                    // 3240
    double* S1g = Ep + NGEO*NPHI*DIMS;               // 20
    double* S1p = S1g + NGEO;                        // 540
    float* Uws  = (float*)(S1p + NGEO*NPHI);         // NMAT*USTRIDE floats
    float* Vws  = Uws + (size_t)NMAT*USTRIDE;        // NMAT*256 floats
    int*   e_idx = (int*)(Vws + (size_t)NMAT*256);   // NTEST
    int*   g_idx = e_idx + NTEST;                    // NTEST
    int*   list  = g_idx + NTEST;                    // NMAT
    int*   cnt   = list + NMAT;                      // 1
    float* out = (float*)d_out;

    void* args[] = {
        (void*)&X_test, (void*)&X_exp, (void*)&Y_exp, (void*)&X_base, (void*)&Y_base,
        (void*)&lls_e, (void*)&los_e, (void*)&lno_e,
        (void*)&lls_b, (void*)&los_b, (void*)&lno_b,
        (void*)&sm, (void*)&ss, (void*)&gm, (void*)&glv, (void*)&glw,
        (void*)&pm, (void*)&plv, (void*)&plw, (void*)&nmask,
        (void*)&Uws, (void*)&Vws, (void*)&e_idx, (void*)&g_idx,
        (void*)&list, (void*)&cnt, (void*)&out };

    hipLaunchCooperativeKernel(mega_kernel, dim3(256), dim3(512), args, 0, stream);
}

// Round 10
// 414.636 us; speedup vs baseline: 1.3612x; 1.3612x over previous
//
#include <hip/hip_runtime.h>
#include <math.h>

// Problem constants
#define DIMS   6
#define NGEO   20
#define NPHI   27
#define NEXPERT 540
#define MPTS   256
#define NTEST  1024
#define NMAT   560          // experts + baselines
#define JIT    1e-4f
#define USTRIDE 33280       // packed padded upper-triangular floats per matrix
#define L2E    1.44269504088896340736f

// Row j of U (cols j..255) starts at uoff(j); each row padded to 4-float multiple.
__device__ __forceinline__ int uoff(int j){
    int m = j >> 2, r = j & 3;
    return 1024*m - 8*m*(m-1) + r*(256 - 4*m);
}

// ---------------------------------------------------------------------------
// Kernel 0: precompute exp(-logvar) and sum(logvar) per GMM cluster in fp64.
// ---------------------------------------------------------------------------
__global__ __launch_bounds__(1024)
void prep_kernel(const float* __restrict__ glv, const float* __restrict__ plv,
                 double* __restrict__ Eg, double* __restrict__ Ep,
                 double* __restrict__ S1g, double* __restrict__ S1p)
{
    int t = threadIdx.x;
    if (t < NGEO*DIMS) Eg[t] = exp(-(double)glv[t]);
    for (int i=t; i<NGEO*NPHI*DIMS; i+=1024) Ep[i] = exp(-(double)plv[i]);
    if (t < NGEO){
        double s = 0.0;
        #pragma unroll
        for (int d=0; d<DIMS; d++) s += (double)glv[t*DIMS+d];
        S1g[t] = s;
    }
    if (t < NGEO*NPHI){
        double s = 0.0;
        #pragma unroll
        for (int d=0; d<DIMS; d++) s += (double)plv[t*DIMS+d];
        S1p[t] = s;
    }
}

// ---------------------------------------------------------------------------
// Kernel 1: 2-level GMM hard routing, fp64 FMA-only (factors precomputed)
// ---------------------------------------------------------------------------
__global__ __launch_bounds__(64)
void route_kernel(const float* __restrict__ Xt, const float* __restrict__ sm,
                  const float* __restrict__ ss,
                  const float* __restrict__ gm, const float* __restrict__ glw,
                  const float* __restrict__ pm, const float* __restrict__ plw,
                  const double* __restrict__ Eg, const double* __restrict__ Ep,
                  const double* __restrict__ S1g, const double* __restrict__ S1p,
                  int* __restrict__ e_idx, int* __restrict__ g_idx)
{
    int n = blockIdx.x*64 + threadIdx.x;
    if (n >= NTEST) return;
    double xs[DIMS];
    #pragma unroll
    for (int d=0; d<DIMS; d++)
        xs[d] = ((double)Xt[n*DIMS+d] - (double)sm[d]) / (double)ss[d];
    const double cst = (double)DIMS * 1.8378770664093453;  // D*log(2*pi)

    int bg = 0; double best = -1e300;
    for (int j=0; j<NGEO; j++){
        double q = 0.0;
        #pragma unroll
        for (int d=0; d<DIMS; d++){
            double df = xs[d] - (double)gm[j*DIMS+d];
            q += df*df*Eg[j*DIMS+d];
        }
        double lp = (double)glw[j] - 0.5*(S1g[j] + q + cst);
        if (lp > best){ best = lp; bg = j; }
    }
    int bk = 0; best = -1e300;
    for (int k=0; k<NPHI; k++){
        double q = 0.0;
        int o = (bg*NPHI + k)*DIMS;
        #pragma unroll
        for (int d=0; d<DIMS; d++){
            double df = xs[d] - (double)pm[o+d];
            q += df*df*Ep[o+d];
        }
        double lp = (double)plw[bg*NPHI+k] - 0.5*(S1p[bg*NPHI+k] + q + cst);
        if (lp > best){ best = lp; bk = k; }
    }
    e_idx[n] = bg*NPHI + bk;
    g_idx[n] = bg;
}

// ---------------------------------------------------------------------------
// Kernel 1b: chol worklist + PREDICT TASK SORT. Tasks = (side,point):
// expert task id = n, baseline task id = 1024+n, keyed by matrix bidx.
// Counting sort groups tasks by matrix; chunks of <=4 tasks feed
// predict2's 4-RHS-per-wave solve (L loads shared across RHS).
// ---------------------------------------------------------------------------
__global__ __launch_bounds__(1024)
void compact_kernel(const int* __restrict__ e_idx, const int* __restrict__ g_idx,
                    const int* __restrict__ nullmask,
                    int* __restrict__ list, int* __restrict__ cnt,
                    int* __restrict__ ord, int* __restrict__ chst,
                    int* __restrict__ chmt, int* __restrict__ nchk)
{
    __shared__ int flags[NMAT];
    __shared__ int s[1024];
    __shared__ int tcnt[NMAT];
    __shared__ int toff[NMAT];
    __shared__ int woff[NMAT];
    int t = threadIdx.x;
    if (t < NEXPERT) flags[t] = 0;
    else if (t < NMAT) flags[t] = 1;       // baselines always needed
    if (t < NMAT) tcnt[t] = 0;
    __syncthreads();
    int e = e_idx[t];                      // t in [0,NTEST)
    int g = g_idx[t];
    if (nullmask[e] != 0) flags[e] = 1;    // benign race: same value
    atomicAdd(&tcnt[e], 1);                // expert-side task
    atomicAdd(&tcnt[NEXPERT + g], 1);      // baseline-side task
    __syncthreads();
    // ---- chol worklist scan (unchanged semantics/order) ----
    int nd = (t < NMAT) ? flags[t] : 0;
    s[t] = nd;
    __syncthreads();
    for (int off=1; off<1024; off<<=1){
        int v = (t >= off) ? s[t-off] : 0;
        __syncthreads();
        s[t] += v;
        __syncthreads();
    }
    if (nd) list[s[t]-1] = t;
    if (t == NMAT-1) cnt[0] = s[t];
    __syncthreads();
    // ---- task offset scan ----
    int tc = (t < NMAT) ? tcnt[t] : 0;
    s[t] = tc;
    __syncthreads();
    for (int off=1; off<1024; off<<=1){
        int v = (t >= off) ? s[t-off] : 0;
        __syncthreads();
        s[t] += v;
        __syncthreads();
    }
    if (t < NMAT){ toff[t] = s[t] - tc; woff[t] = s[t] - tc; }
    __syncthreads();
    // ---- scatter tasks (order within a matrix irrelevant) ----
    int p0 = atomicAdd(&woff[e], 1);
    ord[p0] = t;                           // expert side
    int p1 = atomicAdd(&woff[NEXPERT + g], 1);
    ord[p1] = 1024 + t;                    // baseline side
    __syncthreads();
    // ---- chunk scan (chunks of <=4 same-matrix tasks) ----
    int nch = (t < NMAT) ? ((tcnt[t] + 3) >> 2) : 0;
    s[t] = nch;
    __syncthreads();
    for (int off=1; off<1024; off<<=1){
        int v = (t >= off) ? s[t-off] : 0;
        __syncthreads();
        s[t] += v;
        __syncthreads();
    }
    if (t < NMAT){
        int cb = s[t] - nch;
        for (int i=0; i<nch; i++){
            chst[cb+i] = toff[t] + 4*i;
            int rem = tcnt[t] - 4*i;
            chmt[cb+i] = t*8 + (rem > 4 ? 4 : rem);
        }
    }
    if (t == 1023) nchk[0] = s[1023];
}

// ---------------------------------------------------------------------------
// Kernel 2: left-looking Cholesky (FROZEN r2 237us code, untouched).
// ---------------------------------------------------------------------------
__global__ __launch_bounds__(512)
void chol_kernel(const float* __restrict__ X_exp, const float* __restrict__ Y_exp,
                 const float* __restrict__ X_base, const float* __restrict__ Y_base,
                 const float* __restrict__ lls_e, const float* __restrict__ los_e,
                 const float* __restrict__ lno_e,
                 const float* __restrict__ lls_b, const float* __restrict__ los_b,
                 const float* __restrict__ lno_b,
                 const int* __restrict__ list, const int* __restrict__ cnt,
                 float* __restrict__ Uws, float* __restrict__ Vws)
{
    __shared__ __align__(16) float Xs[256*8];    // 8 KB   train points, stride 8
    __shared__ __align__(16) float Bs[7*1024];   // 28 KB  staged B diag-col blocks
    __shared__ __align__(16) float Part[256*36]; // 36 KB  secondary partials
    __shared__ float Dl[32*36];                  // diag block of L
    __shared__ float Dinv[32];                   // 1/diag(L)

    int t = threadIdx.x;
    int w = t >> 6, lane = t & 63;
    bool prim = (t < 256);
    int nwork = cnt[0];

    for (int item = blockIdx.x; item < nwork; item += gridDim.x){
    int mat = list[item];
    int q = ((w & 3) + item) & 3;                // column chunk (team-matched)
    int c = 64*q + lane;                         // owned column

    const float *Xtr, *Ytr;
    float lls, los, lno;
    if (mat < NEXPERT){
        Xtr = X_exp + mat*(MPTS*DIMS); Ytr = Y_exp + mat*MPTS;
        lls = lls_e[mat]; los = los_e[mat]; lno = lno_e[mat];
    } else {
        int g = mat - NEXPERT;
        Xtr = X_base + g*(MPTS*DIMS); Ytr = Y_base + g*MPTS;
        lls = lls_b[g]; los = los_b[g]; lno = lno_b[g];
    }
    float ls2 = expf(2.f*lls);
    float os  = expf(los);
    float nv  = expf(lno) + JIT;
    float c1  = -0.5f*L2E/ls2;
    float* Ug = Uws + (size_t)mat*USTRIDE;

    // stage X into LDS (padded stride 8; slots 6,7 never read)
    for (int i=t; i<MPTS*DIMS; i+=512){ int r=i/DIMS, d=i-r*DIMS; Xs[r*8+d]=Xtr[i]; }

    for (int j=0; j<8; j++){
        __syncthreads();   // prev panel's Bs/Part reads done + stores drained

        // ---- async-stage B blocks for this panel (all 8 waves) ----
        for (int u=w; u<16*j; u+=8){
            int blk = u >> 4, e0 = (u & 15)*64;
            int m  = 2*(u & 15) + (lane >> 5);
            int kk = lane & 31;
            int ri = 32*blk + m;
            const float* gp = Ug + (uoff(ri) + 32*j + kk - ri);
            __builtin_amdgcn_global_load_lds(
                (const __attribute__((address_space(1))) void*)gp,
                (__attribute__((address_space(3))) void*)&Bs[blk*1024 + e0],
                4, 0, 0);
        }

        int l = c - 32*j;                // diag-local index of owned column
        bool act = (l >= 0);
        int jh = j >> 1;                 // primary panels: [0,jh); secondary: [jh,j)
        float x[32];                     // primary: column value; secondary: partial

        // ---- build original K entries (primary; overlaps staging) ----
        if (prim && act){
            float4 xa = *(const float4*)&Xs[c*8];
            float2 xb = *(const float2*)&Xs[c*8+4];
            #pragma unroll
            for (int k=0; k<32; k++){
                const float* Xr = &Xs[(32*j+k)*8];
                float4 ra = *(const float4*)Xr;
                float2 rb = *(const float2*)(Xr+4);
                float d0=xa.x-ra.x, d1=xa.y-ra.y, d2v=xa.z-ra.z, d3=xa.w-ra.w;
                float d4=xb.x-rb.x, d5=xb.y-rb.y;
                float dd = d0*d0+d1*d1+d2v*d2v+d3*d3+d4*d4+d5*d5;
                float val = os*exp2f(c1*dd);
                if (k == l) val += nv;   // diagonal
                x[k] = val;
            }
        } else {
            #pragma unroll
            for (int k=0; k<32; k++) x[k] = 0.f;   // secondary partial
        }
        __syncthreads();   // staging drained (vmcnt 0) -> Bs valid

        // ---- update: team-split over prev panels ----
        if (act){
            int i0 = prim ? 0 : jh;
            int i1 = prim ? jh : j;
            for (int i2=i0; i2<i1; i2++){
                float a[32];
                #pragma unroll
                for (int m=0; m<32; m++){
                    int ri = 32*i2 + m;
                    a[m] = Ug[uoff(ri) + c - ri];     // U[ri][c]
                }
                #pragma unroll 8
                for (int m=0; m<32; m++){
                    const float4* Bp = (const float4*)&Bs[i2*1024 + m*32];
                    float nam = -a[m];
                    #pragma unroll
                    for (int kk=0; kk<8; kk++){
                        float4 bb = Bp[kk];           // broadcast, conflict-free
                        x[kk*4+0] = fmaf(bb.x, nam, x[kk*4+0]);
                        x[kk*4+1] = fmaf(bb.y, nam, x[kk*4+1]);
                        x[kk*4+2] = fmaf(bb.z, nam, x[kk*4+2]);
                        x[kk*4+3] = fmaf(bb.w, nam, x[kk*4+3]);
                    }
                }
            }
            // secondary publishes its partial
            if (!prim && j > jh){
                float4* Pp = (float4*)&Part[c*36];
                #pragma unroll
                for (int kk=0; kk<8; kk++)
                    Pp[kk] = make_float4(x[kk*4+0], x[kk*4+1], x[kk*4+2], x[kk*4+3]);
            }
        }
        __syncthreads();   // Part ready

        // ---- combine (primary only) ----
        if (prim && act && j > jh){
            const float4* Pp = (const float4*)&Part[c*36];
            #pragma unroll
            for (int kk=0; kk<8; kk++){
                float4 pv = Pp[kk];
                x[kk*4+0] += pv.x; x[kk*4+1] += pv.y;
                x[kk*4+2] += pv.z; x[kk*4+3] += pv.w;
            }
        }

        // ---- diag 32x32 factor: owning primary half-wave, shfl only ----
        if (prim && l >= 0 && l < 32){
            int lb = 32*(j & 1);          // lane base of the diag group
            float r[32];
            #pragma unroll
            for (int k=0; k<32; k++) r[k] = (k <= l) ? x[k] : 0.f;
            float myinv = 1.f;
            #pragma unroll
            for (int cc=0; cc<32; cc++){
                float pivsq = __shfl(r[cc], lb + cc);
                float inv = rsqrtf(pivsq);
                r[cc] *= inv;
                if (l == cc) myinv = inv;
                #pragma unroll
                for (int k=cc+1; k<32; k++) r[k] -= r[cc]*__shfl(r[cc], lb + k);
            }
            Dinv[l] = myinv;
            #pragma unroll
            for (int k=0; k<32; k++){
                if (k <= l) Dl[l*36 + k] = r[k];
                x[k] = r[k];
            }
        }
        __syncthreads();                  // Dl/Dinv visible
        // ---- trsm: in-thread, D via LDS broadcast ----
        if (prim && l >= 32){
            #pragma unroll
            for (int cc=0; cc<32; cc++){
                float a = x[cc]*Dinv[cc];
                x[cc] = a;
                #pragma unroll
                for (int k=cc+1; k<32; k++)
                    x[k] -= Dl[k*36 + cc]*a;
            }
        }
        // ---- store panel column to global (once) ----
        if (prim && act){
            #pragma unroll
            for (int k=0; k<32; k++){
                if (l >= k) Ug[uoff(32*j+k) + l - k] = x[k];
            }
        }
    }
    __syncthreads();

    // v = L^-1 y  (forward solve, wave 0 only; L columns = U rows, coalesced)
    if (t < 64){
        int l = t;
        float z[4], rd[4];
        #pragma unroll
        for (int qq2=0; qq2<4; qq2++){
            z[qq2]  = Ytr[64*qq2 + l];
            rd[qq2] = 1.f/Ug[uoff(64*qq2 + l)];
        }
        int offj = 0;
        #pragma unroll
        for (int qq2=0; qq2<4; qq2++){
            for (int j2=0; j2<64; j2++){
                int j = 64*qq2 + j2;
                float zf = __shfl(z[qq2], j2) * __shfl(rd[qq2], j2);
                if (l == j2) z[qq2] = zf;
                #pragma unroll
                for (int r=qq2; r<4; r++){
                    int dd = 64*(r-qq2) + (l - j2);
                    int dc = dd > 0 ? dd : 0;
                    float uv = Ug[offj + dc];
                    if (dd > 0) z[r] -= uv*zf;
                }
                offj += (259-j)&~3;
            }
        }
        #pragma unroll
        for (int qq2=0; qq2<4; qq2++) Vws[mat*256 + 64*qq2 + l] = z[qq2];
    }
    __syncthreads();   // safe LDS reuse for next work item
    }
}

// ---------------------------------------------------------------------------
// Kernel 3: predict v2 — 4 RHS per wave, all from the SAME matrix.
// L loads (the latency cost: ~17MB working set spread over 8 private L2s,
// mostly L3-latency) are SHARED across the 4 RHS; the 4 zf-composition
// chains are independent -> 4x ILP on the previously serial chain.
// Per-RHS fma/shfl order is bit-identical to the proven single-RHS kernel.
// ---------------------------------------------------------------------------
__global__ __launch_bounds__(256)
void predict2_kernel(const float* __restrict__ Xt,
                     const float* __restrict__ X_exp, const float* __restrict__ X_base,
                     const float* __restrict__ lls_e, const float* __restrict__ los_e,
                     const float* __restrict__ lno_e,
                     const float* __restrict__ lls_b, const float* __restrict__ los_b,
                     const float* __restrict__ lno_b,
                     const int* __restrict__ nullmask,
                     const float* __restrict__ Uws, const float* __restrict__ Vws,
                     const int* __restrict__ ord, const int* __restrict__ chst,
                     const int* __restrict__ chmt, const int* __restrict__ nchk,
                     float* __restrict__ muA, float* __restrict__ varA,
                     float* __restrict__ prA)
{
    int lw = threadIdx.x >> 6, l = threadIdx.x & 63;
    int wt = blockIdx.x*4 + lw;
    if (wt >= nchk[0]) return;     // no __syncthreads below: safe divergence
    int meta = chmt[wt];
    int bidx = meta >> 3, cntc = meta & 7;
    int st = chst[wt];
    int task[4];
    #pragma unroll
    for (int r=0; r<4; r++) task[r] = ord[st + (r < cntc ? r : cntc-1)];

    const float* Xtr; float lls, los, lno;
    if (bidx < NEXPERT){
        Xtr = X_exp + bidx*(MPTS*DIMS);
        lls = lls_e[bidx]; los = los_e[bidx]; lno = lno_e[bidx];
    } else {
        int g = bidx - NEXPERT;
        Xtr = X_base + g*(MPTS*DIMS);
        lls = lls_b[g]; los = los_b[g]; lno = lno_b[g];
    }
    float ls2 = expf(2.f*lls), os = expf(los), nv = expf(lno) + JIT;
    float c1 = -0.5f*L2E/ls2;

    // null is chunk-uniform (all tasks in a chunk share bidx)
    if (bidx < NEXPERT && nullmask[bidx] == 0){
        if (l == 0){
            #pragma unroll
            for (int r=0; r<4; r++){
                int tk = task[r];
                muA[tk] = 0.f; varA[tk] = os + nv; prA[tk] = os + nv;
            }
        }
        return;
    }
    const float* Ug = Uws + (size_t)bidx*USTRIDE;
    const float* vv = Vws + bidx*256;

    // k* per RHS (Xtr row loads shared across RHS) + diag reciprocals
    float z[4][4], rd[4];
    float xt[4][DIMS];
    #pragma unroll
    for (int r=0; r<4; r++){
        int n = task[r] & 1023;
        #pragma unroll
        for (int d=0; d<DIMS; d++) xt[r][d] = Xt[n*DIMS + d];
    }
    #pragma unroll
    for (int q=0; q<4; q++){
        int m = 64*q + l;
        rd[q] = 1.f/Ug[uoff(m)];
        float xr[DIMS];
        #pragma unroll
        for (int d=0; d<DIMS; d++) xr[d] = Xtr[m*DIMS + d];
        #pragma unroll
        for (int r=0; r<4; r++){
            float d2 = 0.f;
            #pragma unroll
            for (int d=0; d<DIMS; d++){ float df = xt[r][d]-xr[d]; d2 += df*df; }
            z[r][q] = os*exp2f(c1*d2);
        }
    }
    // w = L^-1 k*  (forward solve, 4-column pivot groups, 4 RHS interleaved)
    int offj = 0;
    #pragma unroll
    for (int q=0; q<4; q++){
        #pragma unroll 4
        for (int g=0; g<16; g++){
            int j2 = 4*g;
            int jr = 64*q + j2;
            int off0 = offj;
            int off1 = off0 + ((259-jr)&~3);
            int off2 = off1 + ((258-jr)&~3);
            int off3 = off2 + ((257-jr)&~3);
            float r0 = __shfl(rd[q], j2+0), r1 = __shfl(rd[q], j2+1);
            float r2 = __shfl(rd[q], j2+2), r3 = __shfl(rd[q], j2+3);
            float L10 = Ug[off0+1], L20 = Ug[off0+2], L30 = Ug[off0+3];
            float L21 = Ug[off1+1], L31 = Ug[off1+2];
            float L32 = Ug[off2+1];
            float zf0[4], zf1[4], zf2[4], zf3[4];
            #pragma unroll
            for (int r=0; r<4; r++){
                float a0 = __shfl(z[r][q], j2+0), a1 = __shfl(z[r][q], j2+1);
                float a2 = __shfl(z[r][q], j2+2), a3 = __shfl(z[r][q], j2+3);
                zf0[r] = a0*r0;
                zf1[r] = (a1 - L10*zf0[r])*r1;
                zf2[r] = ((a2 - L20*zf0[r]) - L21*zf1[r])*r2;
                zf3[r] = (((a3 - L30*zf0[r]) - L31*zf1[r]) - L32*zf2[r])*r3;
                if (l == j2+0) z[r][q] = zf0[r];
                if (l == j2+1) z[r][q] = zf1[r];
                if (l == j2+2) z[r][q] = zf2[r];
                if (l == j2+3) z[r][q] = zf3[r];
            }
            if (l >= j2+4){
                float u0 = Ug[off0 + (l - j2)];
                float u1 = Ug[off1 + (l - j2 - 1)];
                float u2 = Ug[off2 + (l - j2 - 2)];
                float u3 = Ug[off3 + (l - j2 - 3)];
                #pragma unroll
                for (int r=0; r<4; r++){
                    z[r][q] -= u0*zf0[r];
                    z[r][q] -= u1*zf1[r];
                    z[r][q] -= u2*zf2[r];
                    z[r][q] -= u3*zf3[r];
                }
            }
            #pragma unroll
            for (int rr=q+1; rr<4; rr++){
                int dd = 64*(rr-q) + (l - j2);
                float u0 = Ug[off0 + dd];
                float u1 = Ug[off1 + dd - 1];
                float u2 = Ug[off2 + dd - 2];
                float u3 = Ug[off3 + dd - 3];
                #pragma unroll
                for (int r=0; r<4; r++){
                    z[r][rr] -= u0*zf0[r];
                    z[r][rr] -= u1*zf1[r];
                    z[r][rr] -= u2*zf2[r];
                    z[r][rr] -= u3*zf3[r];
                }
            }
            offj = off3 + ((256-jr)&~3);
        }
    }
    // reductions per RHS (vv loads shared)
    float vl[4];
    #pragma unroll
    for (int q=0; q<4; q++) vl[q] = vv[64*q + l];
    #pragma unroll
    for (int r=0; r<4; r++){
        float qq = 0.f, mu = 0.f;
        #pragma unroll
        for (int q=0; q<4; q++){ qq += z[r][q]*z[r][q]; mu += z[r][q]*vl[q]; }
        #pragma unroll
        for (int o=32; o>0; o>>=1){ qq += __shfl_xor(qq, o); mu += __shfl_xor(mu, o); }
        if (l == 0){
            int tk = task[r];              // duplicates rewrite identical values
            muA[tk]  = mu;
            varA[tk] = fmaxf(os - qq, JIT) + nv;
            prA[tk]  = os + nv;
        }
    }
}

// ---------------------------------------------------------------------------
// Kernel 4: rBCM combine (same formulas as before)
// ---------------------------------------------------------------------------
__global__ __launch_bounds__(256)
void combine_kernel(const int* __restrict__ e_idx, const int* __restrict__ nullmask,
                    const float* __restrict__ muA, const float* __restrict__ varA,
                    const float* __restrict__ prA, float* __restrict__ out)
{
    int n = blockIdx.x*256 + threadIdx.x;
    if (n >= NTEST) return;
    float mu_e = muA[n],        var_e = varA[n],        pr_e = prA[n];
    float mu_b = muA[1024 + n], var_b = varA[1024 + n], pr_b = prA[1024 + n];
    int ee = e_idx[n];
    float be = (nullmask[ee] == 0) ? 0.f
             : fmaxf(0.5f*(logf(pr_e) - logf(var_e)), 0.f);
    float bb = fmaxf(0.5f*(logf(pr_b) - logf(var_b)), 0.f);
    float prec = be/var_e + bb/var_b + (1.f - be - bb)/pr_b;
    prec = fmaxf(prec, 1e-6f);
    out[n]         = (be*mu_e/var_e + bb*mu_b/var_b)/prec;
    out[NTEST + n] = 1.f/prec;
}

// ---------------------------------------------------------------------------
extern "C" void kernel_launch(void* const* d_in, const int* in_sizes, int n_in,
                              void* d_out, int out_size, void* d_ws, size_t ws_size,
                              hipStream_t stream)
{
    const float* X_test  = (const float*)d_in[0];
    const float* X_exp   = (const float*)d_in[1];
    const float* Y_exp   = (const float*)d_in[2];
    const float* X_base  = (const float*)d_in[3];
    const float* Y_base  = (const float*)d_in[4];
    const float* lls_e   = (const float*)d_in[5];
    const float* los_e   = (const float*)d_in[6];
    const float* lno_e   = (const float*)d_in[7];
    const float* lls_b   = (const float*)d_in[8];
    const float* los_b   = (const float*)d_in[9];
    const float* lno_b   = (const float*)d_in[10];
    const float* sm      = (const float*)d_in[11];
    const float* ss      = (const float*)d_in[12];
    const float* gm      = (const float*)d_in[13];
    const float* glv     = (const float*)d_in[14];
    const float* glw     = (const float*)d_in[15];
    const float* pm      = (const float*)d_in[16];
    const float* plv     = (const float*)d_in[17];
    const float* plw     = (const float*)d_in[18];
    const int*   nmask   = (const int*)d_in[19];

    // ws layout: doubles first (8-aligned), then big float arrays, then ints
    double* Eg  = (double*)d_ws;                     // 120
    double* Ep  = Eg + NGEO*DIMS;                    // 3240
    double* S1g = Ep + NGEO*NPHI*DIMS;               // 20
    double* S1p = S1g + NGEO;                        // 540
    float* Uws  = (float*)(S1p + NGEO*NPHI);         // NMAT*USTRIDE floats
    float* Vws  = Uws + (size_t)NMAT*USTRIDE;        // NMAT*256 floats
    int*   e_idx = (int*)(Vws + (size_t)NMAT*256);   // NTEST
    int*   g_idx = e_idx + NTEST;                    // NTEST
    int*   list  = g_idx + NTEST;                    // NMAT
    int*   cnt   = list + NMAT;                      // 1
    int*   ord   = cnt + 1;                          // 2048 task ids
    int*   chst  = ord + 2048;                       // 2048 chunk starts
    int*   chmt  = chst + 2048;                      // 2048 chunk meta
    int*   nchk  = chmt + 2048;                      // 1
    float* muA   = (float*)(nchk + 1);               // 2048
    float* varA  = muA + 2048;                       // 2048
    float* prA   = varA + 2048;                      // 2048
    float* out = (float*)d_out;

    prep_kernel<<<dim3(1), dim3(1024), 0, stream>>>(glv, plv, Eg, Ep, S1g, S1p);
    route_kernel<<<dim3(NTEST/64), dim3(64), 0, stream>>>(
        X_test, sm, ss, gm, glw, pm, plw, Eg, Ep, S1g, S1p, e_idx, g_idx);
    compact_kernel<<<dim3(1), dim3(1024), 0, stream>>>(
        e_idx, g_idx, nmask, list, cnt, ord, chst, chmt, nchk);
    chol_kernel<<<dim3(256), dim3(512), 0, stream>>>(
        X_exp, Y_exp, X_base, Y_base,
        lls_e, los_e, lno_e, lls_b, los_b, lno_b, list, cnt, Uws, Vws);
    predict2_kernel<<<dim3(512), dim3(256), 0, stream>>>(
        X_test, X_exp, X_base,
        lls_e, los_e, lno_e, lls_b, los_b, lno_b,
        nmask, Uws, Vws, ord, chst, chmt, nchk, muA, varA, prA);
    combine_kernel<<<dim3(NTEST/256), dim3(256), 0, stream>>>(
        e_idx, nmask, muA, varA, prA, out);
}